// Round 2
// baseline (1293.063 us; speedup 1.0000x reference)
//
#include <hip/hip_runtime.h>
#include <hip/hip_bf16.h>

// Capsule routing: B=64, R=2048, C=32, O=32, I=32, 3 iterations.
// u_hat never materialized: recomputed per pass from bf16 W via MFMA.
// Round 2: no atomics, no memsets. s-passes write exclusive partial tiles,
// fused reduce+squash; pass-0 fused with W f32->bf16 conversion; a-pass
// uses LDS pair-matrix reduction and owns its bb[c][r] slice exclusively.

#define B_  64
#define R_  2048
#define CI  32     // in channels (K)
#define NC  32     // num capsules
#define OC  32     // out channels
#define NCO 1024   // NC*OC, the N dimension
#define RPB 32     // routes per block
#define GR  (R_ / RPB)   // 64 blocks in r-dim
#define BN  65536  // B_*NCO elements of s/v

typedef __attribute__((ext_vector_type(8))) short bf16x8;
typedef __attribute__((ext_vector_type(4))) float f32x4;

static constexpr long WN = (long)R_ * NCO * CI;  // 67,108,864
static constexpr long XN = (long)B_ * R_ * CI;   // 4,194,304

__device__ __forceinline__ unsigned short rne_bf16(float f) {
  unsigned int u = __builtin_bit_cast(unsigned int, f);
  u += 0x7fffu + ((u >> 16) & 1u);   // round-to-nearest-even (finite inputs)
  return (unsigned short)(u >> 16);
}

__device__ __forceinline__ bf16x8 pack8(float4 a, float4 b) {
  bf16x8 r;
  r[0] = (short)rne_bf16(a.x); r[1] = (short)rne_bf16(a.y);
  r[2] = (short)rne_bf16(a.z); r[3] = (short)rne_bf16(a.w);
  r[4] = (short)rne_bf16(b.x); r[5] = (short)rne_bf16(b.y);
  r[6] = (short)rne_bf16(b.z); r[7] = (short)rne_bf16(b.w);
  return r;
}

// f32 -> bf16, vectorized (n4 = n/4) — used for x only
__global__ __launch_bounds__(256) void cvt_kernel(const float* __restrict__ src,
                                                  unsigned short* __restrict__ dst,
                                                  int n4) {
  int i = blockIdx.x * blockDim.x + threadIdx.x;
  int stride = gridDim.x * blockDim.x;
  const float4* s4 = (const float4*)src;
  ushort4* d4 = (ushort4*)dst;
  for (; i < n4; i += stride) {
    float4 f = s4[i];
    ushort4 u;
    u.x = rne_bf16(f.x); u.y = rne_bf16(f.y);
    u.z = rne_bf16(f.z); u.w = rne_bf16(f.w);
    d4[i] = u;
  }
}

// Pass 0 s-pass fused with W conversion: c is uniform 1/2048 so accumulate
// straight in the MFMA C operand and scale at the epilogue. Reads W f32,
// converts inline, optionally stores Wb for later passes.
// grid (GR, 4), block 256: wave mw = M-tile, blockIdx.y = g (8 capsules).
template<bool STORE_WB>
__global__ __launch_bounds__(256) void s0_kernel(
    const float* __restrict__ x, const float* __restrict__ W,
    unsigned short* __restrict__ Wb,
    float* __restrict__ part) {          // [GR][B_][NCO]
  const int tid  = threadIdx.x;
  const int lane = tid & 63;
  const int mw   = tid >> 6;
  const int g    = blockIdx.y;
  const int r0   = blockIdx.x * RPB;
  const int l15  = lane & 15;
  const int q    = lane >> 4;
  const int k0   = q * 8;
  const int bA   = mw * 16 + l15;

  f32x4 acc[16];
#pragma unroll
  for (int t = 0; t < 16; ++t) acc[t] = (f32x4){0.f, 0.f, 0.f, 0.f};

#pragma unroll 4
  for (int j = 0; j < RPB; ++j) {
    const int r = r0 + j;
    const float* xp = x + ((bA * R_ + r) * CI + k0);
    bf16x8 af = pack8(*(const float4*)xp, *(const float4*)(xp + 4));
#pragma unroll
    for (int t = 0; t < 16; ++t) {
      const int nrow = (g * 16 + t) * 16 + l15;
      const int off = (r * NCO + nrow) * CI + k0;
      const float* wp = W + off;
      bf16x8 bfr = pack8(*(const float4*)wp, *(const float4*)(wp + 4));
      if (STORE_WB && mw == (j & 3))
        *(bf16x8*)(Wb + off) = bfr;       // each fragment stored exactly once
      acc[t] = __builtin_amdgcn_mfma_f32_16x16x32_bf16(af, bfr, acc[t], 0, 0, 0);
    }
  }
  // C/D layout: row(m) = (lane>>4)*4 + reg, col(n) = lane&15
  const int pbase = blockIdx.x * BN;
#pragma unroll
  for (int t = 0; t < 16; ++t) {
    const int n = (g * 16 + t) * 16 + l15;
#pragma unroll
    for (int rr = 0; rr < 4; ++rr) {
      const int b = mw * 16 + q * 4 + rr;
      part[pbase + b * NCO + n] = acc[t][rr] * (1.0f / 2048.0f);
    }
  }
}

// s-pass for iterations 1,2: s[b,c,o] partial = sum_r c[r,c]*(W[r,c,o,:].x[b,r,:])
template<bool FAST>
__global__ __launch_bounds__(256) void s_kernel(
    const float* __restrict__ x, const float* __restrict__ W,
    const unsigned short* __restrict__ xb, const unsigned short* __restrict__ Wb,
    const float* __restrict__ cmat,   // [C][R]
    float* __restrict__ part) {       // [GR][B_][NCO]
  const int tid  = threadIdx.x;
  const int lane = tid & 63;
  const int mw   = tid >> 6;
  const int g    = blockIdx.y;
  const int r0   = blockIdx.x * RPB;
  const int l15  = lane & 15;
  const int q    = lane >> 4;
  const int k0   = q * 8;
  const int bA   = mw * 16 + l15;

  f32x4 acc[16];
#pragma unroll
  for (int t = 0; t < 16; ++t) acc[t] = (f32x4){0.f, 0.f, 0.f, 0.f};
  const f32x4 zero4 = (f32x4){0.f, 0.f, 0.f, 0.f};

  for (int j = 0; j < RPB; ++j) {
    const int r = r0 + j;
    bf16x8 af;
    if (FAST) {
      af = *(const bf16x8*)(xb + ((bA * R_ + r) * CI + k0));
    } else {
      const float* xp = x + ((bA * R_ + r) * CI + k0);
      af = pack8(*(const float4*)xp, *(const float4*)(xp + 4));
    }
    float cv[8];
#pragma unroll
    for (int cc = 0; cc < 8; ++cc) cv[cc] = cmat[(g * 8 + cc) * R_ + r];
#pragma unroll
    for (int t = 0; t < 16; ++t) {
      const int nrow = (g * 16 + t) * 16 + l15;
      bf16x8 bfr;
      if (FAST) {
        bfr = *(const bf16x8*)(Wb + (r * NCO + nrow) * CI + k0);
      } else {
        const float* wp = W + (r * NCO + nrow) * CI + k0;
        bfr = pack8(*(const float4*)wp, *(const float4*)(wp + 4));
      }
      f32x4 u = __builtin_amdgcn_mfma_f32_16x16x32_bf16(af, bfr, zero4, 0, 0, 0);
      acc[t] += cv[t >> 1] * u;    // capsule const within 16-wide n-tile (O=32)
    }
  }
  const int pbase = blockIdx.x * BN;
#pragma unroll
  for (int t = 0; t < 16; ++t) {
    const int n = (g * 16 + t) * 16 + l15;
#pragma unroll
    for (int rr = 0; rr < 4; ++rr) {
      const int b = mw * 16 + q * 4 + rr;
      part[pbase + b * NCO + n] = acc[t][rr];
    }
  }
}

// reduce partials over GR slices + squash (exact reference formula)
__global__ __launch_bounds__(256) void rs_kernel(const float* __restrict__ part,
                                                 float* __restrict__ o) {
  const int i = blockIdx.x * 256 + threadIdx.x;
  float a0 = 0.f, a1 = 0.f, a2 = 0.f, a3 = 0.f;
#pragma unroll
  for (int p = 0; p < GR; p += 4) {
    a0 += part[p * BN + i];
    a1 += part[(p + 1) * BN + i];
    a2 += part[(p + 2) * BN + i];
    a3 += part[(p + 3) * BN + i];
  }
  const float sv = (a0 + a1) + (a2 + a3);
  const float sq = sv * sv;
  o[i] = sq * sv / ((1.0f + sq) * sqrtf(sq));
}

// a-pass: bb[c][r] (+)= (1/64) * sum_{b,o} u_hat[b,r,c,o] * v[b,c,o]
// Block (rg,g) exclusively owns bb[g*8..g*8+8][r0..r0+RPB] -> no atomics.
// Cross-lane reduction via LDS pair-matrix (stride-65 pad: conflict-free).
template<bool FAST, bool FIRST>
__global__ __launch_bounds__(256) void a_kernel(
    const float* __restrict__ x, const float* __restrict__ W,
    const unsigned short* __restrict__ xb, const unsigned short* __restrict__ Wb,
    const float* __restrict__ v,    // [B_][NCO]
    float* __restrict__ bb) {       // [C][R]
  const int tid  = threadIdx.x;
  const int lane = tid & 63;
  const int mw   = tid >> 6;
  const int g    = blockIdx.y;
  const int r0   = blockIdx.x * RPB;
  const int l15  = lane & 15;
  const int q    = lane >> 4;
  const int k0   = q * 8;
  const int bA   = mw * 16 + l15;

  // pairs per chunk: 8 capsules x 4 routes = 32; 8 chunks cover 32 routes
  __shared__ float slab[4][32][65];     // [wave][pair][lane] 33.3 KB
  __shared__ float accw[8][4][64];      // [chunk][wave][pair-half] 8 KB

  // preload v in exact MFMA C-layout
  float vreg[16][4];
#pragma unroll
  for (int t = 0; t < 16; ++t) {
    const int n = (g * 16 + t) * 16 + l15;
#pragma unroll
    for (int rr = 0; rr < 4; ++rr)
      vreg[t][rr] = v[(mw * 16 + q * 4 + rr) * NCO + n];
  }
  const f32x4 zero4 = (f32x4){0.f, 0.f, 0.f, 0.f};

  for (int kk = 0; kk < 8; ++kk) {        // 8 chunks of 4 routes
#pragma unroll
    for (int jj = 0; jj < 4; ++jj) {
      const int r = r0 + kk * 4 + jj;
      bf16x8 af;
      if (FAST) {
        af = *(const bf16x8*)(xb + ((bA * R_ + r) * CI + k0));
      } else {
        const float* xp = x + ((bA * R_ + r) * CI + k0);
        af = pack8(*(const float4*)xp, *(const float4*)(xp + 4));
      }
      float dotc[8];
#pragma unroll
      for (int cc = 0; cc < 8; ++cc) dotc[cc] = 0.f;
#pragma unroll
      for (int t = 0; t < 16; ++t) {
        const int nrow = (g * 16 + t) * 16 + l15;
        bf16x8 bfr;
        if (FAST) {
          bfr = *(const bf16x8*)(Wb + (r * NCO + nrow) * CI + k0);
        } else {
          const float* wp = W + (r * NCO + nrow) * CI + k0;
          bfr = pack8(*(const float4*)wp, *(const float4*)(wp + 4));
        }
        f32x4 u = __builtin_amdgcn_mfma_f32_16x16x32_bf16(af, bfr, zero4, 0, 0, 0);
        dotc[t >> 1] += u[0] * vreg[t][0] + u[1] * vreg[t][1] +
                        u[2] * vreg[t][2] + u[3] * vreg[t][3];
      }
      // stash: pair p = cc*4 + jj ; write addr p*65+lane -> stride-1 in lane
#pragma unroll
      for (int cc = 0; cc < 8; ++cc)
        slab[mw][cc * 4 + jj][lane] = dotc[cc];
    }
    // half-reduction: lane -> pair p=lane>>1, half h=lane&1 (32 lanes each)
    {
      const int p = lane >> 1, h = lane & 1;
      float sm = 0.f;
#pragma unroll
      for (int i = 0; i < 32; ++i) sm += slab[mw][p][h * 32 + i];
      accw[kk][mw][lane] = sm;
    }
  }
  __syncthreads();
  // final: 256 threads = 8 chunks x 32 pairs
  {
    const int kk = tid >> 5;
    const int p  = tid & 31;
    float tot = 0.f;
#pragma unroll
    for (int w = 0; w < 4; ++w)
      tot += accw[kk][w][p * 2] + accw[kk][w][p * 2 + 1];
    const int cc = p >> 2, jj = p & 3;
    const int r  = r0 + kk * 4 + jj;
    const int o  = (g * 8 + cc) * R_ + r;
    const float val = tot * (1.0f / 64.0f);
    bb[o] = FIRST ? val : (bb[o] + val);
  }
}

// softmax over routes for each capsule: cmat[c][r] = softmax_r(bb[c][r])
__global__ __launch_bounds__(256) void softmax_kernel(const float* __restrict__ bb,
                                                      float* __restrict__ cmat) {
  const int c = blockIdx.x;
  const int tid = threadIdx.x;
  __shared__ float red[8];
  float m = -1e30f;
  for (int r = tid; r < R_; r += 256) m = fmaxf(m, bb[c * R_ + r]);
#pragma unroll
  for (int s = 1; s < 64; s <<= 1) m = fmaxf(m, __shfl_xor(m, s));
  if ((tid & 63) == 0) red[tid >> 6] = m;
  __syncthreads();
  m = fmaxf(fmaxf(red[0], red[1]), fmaxf(red[2], red[3]));
  float sum = 0.f;
  for (int r = tid; r < R_; r += 256) sum += __expf(bb[c * R_ + r] - m);
#pragma unroll
  for (int s = 1; s < 64; s <<= 1) sum += __shfl_xor(sum, s);
  if ((tid & 63) == 0) red[4 + (tid >> 6)] = sum;
  __syncthreads();
  sum = red[4] + red[5] + red[6] + red[7];
  const float inv = 1.0f / sum;
  for (int r = tid; r < R_; r += 256)
    cmat[c * R_ + r] = __expf(bb[c * R_ + r] - m) * inv;
}

extern "C" void kernel_launch(void* const* d_in, const int* in_sizes, int n_in,
                              void* d_out, int out_size, void* d_ws, size_t ws_size,
                              hipStream_t stream) {
  const float* x = (const float*)d_in[0];   // [64, 2048, 32]
  const float* W = (const float*)d_in[1];   // [2048, 32, 32, 32]
  float* out = (float*)d_out;               // [64, 32, 32, 1]

  char* ws = (char*)d_ws;
  float* bb   = (float*)(ws);                         // 256 KB
  float* cmat = (float*)(ws + (1 << 18));             // 256 KB
  float* vbuf = (float*)(ws + 2 * (size_t)(1 << 18)); // 256 KB
  float* part = (float*)(ws + (1 << 20));             // 16 MB
  unsigned short* Wb = (unsigned short*)(ws + 17 * (size_t)(1 << 20));            // 128 MB
  unsigned short* xb = (unsigned short*)(ws + 17 * (size_t)(1 << 20) + WN * 2);   // 8 MB
  const size_t need_fast = 17 * (size_t)(1 << 20) + (size_t)WN * 2 + (size_t)XN * 2;
  const bool fast = ws_size >= need_fast;

  const dim3 grid(GR, 4);

  if (fast) {
    cvt_kernel<<<1024, 256, 0, stream>>>(x, xb, (int)(XN / 4));
    s0_kernel<true><<<grid, 256, 0, stream>>>(x, W, Wb, part);
  } else {
    s0_kernel<false><<<grid, 256, 0, stream>>>(x, W, Wb, part);
  }
  rs_kernel<<<256, 256, 0, stream>>>(part, vbuf);
  if (fast) a_kernel<true, true><<<grid, 256, 0, stream>>>(x, W, xb, Wb, vbuf, bb);
  else      a_kernel<false, true><<<grid, 256, 0, stream>>>(x, W, xb, Wb, vbuf, bb);
  softmax_kernel<<<NC, 256, 0, stream>>>(bb, cmat);
  if (fast) s_kernel<true><<<grid, 256, 0, stream>>>(x, W, xb, Wb, cmat, part);
  else      s_kernel<false><<<grid, 256, 0, stream>>>(x, W, xb, Wb, cmat, part);
  rs_kernel<<<256, 256, 0, stream>>>(part, vbuf);
  if (fast) a_kernel<true, false><<<grid, 256, 0, stream>>>(x, W, xb, Wb, vbuf, bb);
  else      a_kernel<false, false><<<grid, 256, 0, stream>>>(x, W, xb, Wb, vbuf, bb);
  softmax_kernel<<<NC, 256, 0, stream>>>(bb, cmat);
  if (fast) s_kernel<true><<<grid, 256, 0, stream>>>(x, W, xb, Wb, cmat, part);
  else      s_kernel<false><<<grid, 256, 0, stream>>>(x, W, xb, Wb, cmat, part);
  rs_kernel<<<256, 256, 0, stream>>>(part, out);
}

// Round 3
// 778.824 us; speedup vs baseline: 1.6603x; 1.6603x over previous
//
#include <hip/hip_runtime.h>
#include <hip/hip_bf16.h>

// Capsule routing: B=64, R=2048, C=32, O=32, I=32, 3 iterations.
// u_hat never materialized: recomputed per pass from bf16 W via MFMA.
// Round 3: round-2 structure (no atomics/memsets, fused convert, partial
// tiles + fused reduce/squash) with the grid restored to 1024 blocks
// (RPB=8) for 16 waves/CU — round 2's 256-block grid was latency-starved.

#define B_  64
#define R_  2048
#define CI  32     // in channels (K)
#define NC  32     // num capsules
#define OC  32     // out channels
#define NCO 1024   // NC*OC, the N dimension
#define RPB 8      // routes per block
#define GR  (R_ / RPB)   // 256 blocks in r-dim
#define BN  65536  // B_*NCO elements of s/v

typedef __attribute__((ext_vector_type(8))) short bf16x8;
typedef __attribute__((ext_vector_type(4))) float f32x4;

static constexpr long WN = (long)R_ * NCO * CI;  // 67,108,864
static constexpr long XN = (long)B_ * R_ * CI;   // 4,194,304

__device__ __forceinline__ unsigned short rne_bf16(float f) {
  unsigned int u = __builtin_bit_cast(unsigned int, f);
  u += 0x7fffu + ((u >> 16) & 1u);   // round-to-nearest-even (finite inputs)
  return (unsigned short)(u >> 16);
}

__device__ __forceinline__ bf16x8 pack8(float4 a, float4 b) {
  bf16x8 r;
  r[0] = (short)rne_bf16(a.x); r[1] = (short)rne_bf16(a.y);
  r[2] = (short)rne_bf16(a.z); r[3] = (short)rne_bf16(a.w);
  r[4] = (short)rne_bf16(b.x); r[5] = (short)rne_bf16(b.y);
  r[6] = (short)rne_bf16(b.z); r[7] = (short)rne_bf16(b.w);
  return r;
}

// f32 -> bf16, vectorized (n4 = n/4) — used for x only
__global__ __launch_bounds__(256) void cvt_kernel(const float* __restrict__ src,
                                                  unsigned short* __restrict__ dst,
                                                  int n4) {
  int i = blockIdx.x * blockDim.x + threadIdx.x;
  int stride = gridDim.x * blockDim.x;
  const float4* s4 = (const float4*)src;
  ushort4* d4 = (ushort4*)dst;
  for (; i < n4; i += stride) {
    float4 f = s4[i];
    ushort4 u;
    u.x = rne_bf16(f.x); u.y = rne_bf16(f.y);
    u.z = rne_bf16(f.z); u.w = rne_bf16(f.w);
    d4[i] = u;
  }
}

// Pass 0 s-pass fused with W conversion: c is uniform 1/2048 so accumulate
// straight in the MFMA C operand and scale at the epilogue. Reads W f32,
// converts inline, stores Wb for later passes.
// grid (GR, 4), block 256: wave mw = M-tile, blockIdx.y = g (8 capsules).
template<bool STORE_WB>
__global__ __launch_bounds__(256) void s0_kernel(
    const float* __restrict__ x, const float* __restrict__ W,
    unsigned short* __restrict__ Wb,
    float* __restrict__ part) {          // [GR][B_][NCO]
  const int tid  = threadIdx.x;
  const int lane = tid & 63;
  const int mw   = tid >> 6;
  const int g    = blockIdx.y;
  const int r0   = blockIdx.x * RPB;
  const int l15  = lane & 15;
  const int q    = lane >> 4;
  const int k0   = q * 8;
  const int bA   = mw * 16 + l15;

  f32x4 acc[16];
#pragma unroll
  for (int t = 0; t < 16; ++t) acc[t] = (f32x4){0.f, 0.f, 0.f, 0.f};

#pragma unroll 2
  for (int j = 0; j < RPB; ++j) {
    const int r = r0 + j;
    const float* xp = x + ((bA * R_ + r) * CI + k0);
    bf16x8 af = pack8(*(const float4*)xp, *(const float4*)(xp + 4));
#pragma unroll
    for (int t = 0; t < 16; ++t) {
      const int nrow = (g * 16 + t) * 16 + l15;
      const int off = (r * NCO + nrow) * CI + k0;
      const float* wp = W + off;
      bf16x8 bfr = pack8(*(const float4*)wp, *(const float4*)(wp + 4));
      if (STORE_WB && mw == (j & 3))
        *(bf16x8*)(Wb + off) = bfr;       // each fragment stored exactly once
      acc[t] = __builtin_amdgcn_mfma_f32_16x16x32_bf16(af, bfr, acc[t], 0, 0, 0);
    }
  }
  // C/D layout: row(m) = (lane>>4)*4 + reg, col(n) = lane&15
  const int pbase = blockIdx.x * BN;
#pragma unroll
  for (int t = 0; t < 16; ++t) {
    const int n = (g * 16 + t) * 16 + l15;
#pragma unroll
    for (int rr = 0; rr < 4; ++rr) {
      const int b = mw * 16 + q * 4 + rr;
      part[pbase + b * NCO + n] = acc[t][rr] * (1.0f / 2048.0f);
    }
  }
}

// s-pass for iterations 1,2: s[b,c,o] partial = sum_r c[r,c]*(W[r,c,o,:].x[b,r,:])
template<bool FAST>
__global__ __launch_bounds__(256) void s_kernel(
    const float* __restrict__ x, const float* __restrict__ W,
    const unsigned short* __restrict__ xb, const unsigned short* __restrict__ Wb,
    const float* __restrict__ cmat,   // [C][R]
    float* __restrict__ part) {       // [GR][B_][NCO]
  const int tid  = threadIdx.x;
  const int lane = tid & 63;
  const int mw   = tid >> 6;
  const int g    = blockIdx.y;
  const int r0   = blockIdx.x * RPB;
  const int l15  = lane & 15;
  const int q    = lane >> 4;
  const int k0   = q * 8;
  const int bA   = mw * 16 + l15;

  f32x4 acc[16];
#pragma unroll
  for (int t = 0; t < 16; ++t) acc[t] = (f32x4){0.f, 0.f, 0.f, 0.f};
  const f32x4 zero4 = (f32x4){0.f, 0.f, 0.f, 0.f};

#pragma unroll 2
  for (int j = 0; j < RPB; ++j) {
    const int r = r0 + j;
    bf16x8 af;
    if (FAST) {
      af = *(const bf16x8*)(xb + ((bA * R_ + r) * CI + k0));
    } else {
      const float* xp = x + ((bA * R_ + r) * CI + k0);
      af = pack8(*(const float4*)xp, *(const float4*)(xp + 4));
    }
    float cv[8];
#pragma unroll
    for (int cc = 0; cc < 8; ++cc) cv[cc] = cmat[(g * 8 + cc) * R_ + r];
#pragma unroll
    for (int t = 0; t < 16; ++t) {
      const int nrow = (g * 16 + t) * 16 + l15;
      bf16x8 bfr;
      if (FAST) {
        bfr = *(const bf16x8*)(Wb + (r * NCO + nrow) * CI + k0);
      } else {
        const float* wp = W + (r * NCO + nrow) * CI + k0;
        bfr = pack8(*(const float4*)wp, *(const float4*)(wp + 4));
      }
      f32x4 u = __builtin_amdgcn_mfma_f32_16x16x32_bf16(af, bfr, zero4, 0, 0, 0);
      acc[t] += cv[t >> 1] * u;    // capsule const within 16-wide n-tile (O=32)
    }
  }
  const int pbase = blockIdx.x * BN;
#pragma unroll
  for (int t = 0; t < 16; ++t) {
    const int n = (g * 16 + t) * 16 + l15;
#pragma unroll
    for (int rr = 0; rr < 4; ++rr) {
      const int b = mw * 16 + q * 4 + rr;
      part[pbase + b * NCO + n] = acc[t][rr];
    }
  }
}

// reduce partials over GR slices + squash (exact reference formula)
__global__ __launch_bounds__(256) void rs_kernel(const float* __restrict__ part,
                                                 float* __restrict__ o) {
  const int i = blockIdx.x * 256 + threadIdx.x;
  float a0 = 0.f, a1 = 0.f, a2 = 0.f, a3 = 0.f;
  for (int p = 0; p < GR; p += 4) {
    a0 += part[p * BN + i];
    a1 += part[(p + 1) * BN + i];
    a2 += part[(p + 2) * BN + i];
    a3 += part[(p + 3) * BN + i];
  }
  const float sv = (a0 + a1) + (a2 + a3);
  const float sq = sv * sv;
  o[i] = sq * sv / ((1.0f + sq) * sqrtf(sq));
}

// a-pass: bb[c][r] (+)= (1/64) * sum_{b,o} u_hat[b,r,c,o] * v[b,c,o]
// Block (rg,g) exclusively owns bb[g*8..g*8+8][r0..r0+RPB] -> no atomics.
// Cross-lane reduction via LDS pair-matrix (stride-65 pad: conflict-free).
template<bool FAST, bool FIRST>
__global__ __launch_bounds__(256) void a_kernel(
    const float* __restrict__ x, const float* __restrict__ W,
    const unsigned short* __restrict__ xb, const unsigned short* __restrict__ Wb,
    const float* __restrict__ v,    // [B_][NCO]
    float* __restrict__ bb) {       // [C][R]
  const int tid  = threadIdx.x;
  const int lane = tid & 63;
  const int mw   = tid >> 6;
  const int g    = blockIdx.y;
  const int r0   = blockIdx.x * RPB;
  const int l15  = lane & 15;
  const int q    = lane >> 4;
  const int k0   = q * 8;
  const int bA   = mw * 16 + l15;

  // pairs per chunk: 8 capsules x 4 routes = 32; 2 chunks cover 8 routes
  __shared__ float slab[4][32][65];     // [wave][pair][lane] 33.3 KB
  __shared__ float accw[2][4][64];      // [chunk][wave][pair-half] 2 KB

  // preload v in exact MFMA C-layout
  float vreg[16][4];
#pragma unroll
  for (int t = 0; t < 16; ++t) {
    const int n = (g * 16 + t) * 16 + l15;
#pragma unroll
    for (int rr = 0; rr < 4; ++rr)
      vreg[t][rr] = v[(mw * 16 + q * 4 + rr) * NCO + n];
  }
  const f32x4 zero4 = (f32x4){0.f, 0.f, 0.f, 0.f};

  for (int kk = 0; kk < 2; ++kk) {        // 2 chunks of 4 routes
#pragma unroll
    for (int jj = 0; jj < 4; ++jj) {
      const int r = r0 + kk * 4 + jj;
      bf16x8 af;
      if (FAST) {
        af = *(const bf16x8*)(xb + ((bA * R_ + r) * CI + k0));
      } else {
        const float* xp = x + ((bA * R_ + r) * CI + k0);
        af = pack8(*(const float4*)xp, *(const float4*)(xp + 4));
      }
      float dotc[8];
#pragma unroll
      for (int cc = 0; cc < 8; ++cc) dotc[cc] = 0.f;
#pragma unroll
      for (int t = 0; t < 16; ++t) {
        const int nrow = (g * 16 + t) * 16 + l15;
        bf16x8 bfr;
        if (FAST) {
          bfr = *(const bf16x8*)(Wb + (r * NCO + nrow) * CI + k0);
        } else {
          const float* wp = W + (r * NCO + nrow) * CI + k0;
          bfr = pack8(*(const float4*)wp, *(const float4*)(wp + 4));
        }
        f32x4 u = __builtin_amdgcn_mfma_f32_16x16x32_bf16(af, bfr, zero4, 0, 0, 0);
        dotc[t >> 1] += u[0] * vreg[t][0] + u[1] * vreg[t][1] +
                        u[2] * vreg[t][2] + u[3] * vreg[t][3];
      }
      // stash: pair p = cc*4 + jj ; stride-1 in lane -> conflict-free
#pragma unroll
      for (int cc = 0; cc < 8; ++cc)
        slab[mw][cc * 4 + jj][lane] = dotc[cc];
    }
    // half-reduction: lane -> pair p=lane>>1, half h=lane&1 (32 each)
    {
      const int p = lane >> 1, h = lane & 1;
      float sm = 0.f;
#pragma unroll
      for (int i = 0; i < 32; ++i) sm += slab[mw][p][h * 32 + i];
      accw[kk][mw][lane] = sm;
    }
  }
  __syncthreads();
  // final: 64 threads = 2 chunks x 32 pairs
  if (tid < 64) {
    const int kk = tid >> 5;
    const int p  = tid & 31;
    float tot = 0.f;
#pragma unroll
    for (int w = 0; w < 4; ++w)
      tot += accw[kk][w][p * 2] + accw[kk][w][p * 2 + 1];
    const int cc = p >> 2, jj = p & 3;
    const int r  = r0 + kk * 4 + jj;
    const int o  = (g * 8 + cc) * R_ + r;
    const float val = tot * (1.0f / 64.0f);
    bb[o] = FIRST ? val : (bb[o] + val);
  }
}

// softmax over routes for each capsule: cmat[c][r] = softmax_r(bb[c][r])
__global__ __launch_bounds__(256) void softmax_kernel(const float* __restrict__ bb,
                                                      float* __restrict__ cmat) {
  const int c = blockIdx.x;
  const int tid = threadIdx.x;
  __shared__ float red[8];
  float m = -1e30f;
  for (int r = tid; r < R_; r += 256) m = fmaxf(m, bb[c * R_ + r]);
#pragma unroll
  for (int s = 1; s < 64; s <<= 1) m = fmaxf(m, __shfl_xor(m, s));
  if ((tid & 63) == 0) red[tid >> 6] = m;
  __syncthreads();
  m = fmaxf(fmaxf(red[0], red[1]), fmaxf(red[2], red[3]));
  float sum = 0.f;
  for (int r = tid; r < R_; r += 256) sum += __expf(bb[c * R_ + r] - m);
#pragma unroll
  for (int s = 1; s < 64; s <<= 1) sum += __shfl_xor(sum, s);
  if ((tid & 63) == 0) red[4 + (tid >> 6)] = sum;
  __syncthreads();
  sum = red[4] + red[5] + red[6] + red[7];
  const float inv = 1.0f / sum;
  for (int r = tid; r < R_; r += 256)
    cmat[c * R_ + r] = __expf(bb[c * R_ + r] - m) * inv;
}

extern "C" void kernel_launch(void* const* d_in, const int* in_sizes, int n_in,
                              void* d_out, int out_size, void* d_ws, size_t ws_size,
                              hipStream_t stream) {
  const float* x = (const float*)d_in[0];   // [64, 2048, 32]
  const float* W = (const float*)d_in[1];   // [2048, 32, 32, 32]
  float* out = (float*)d_out;               // [64, 32, 32, 1]

  char* ws = (char*)d_ws;
  float* bb   = (float*)(ws);                         // 256 KB
  float* cmat = (float*)(ws + (1 << 18));             // 256 KB
  float* vbuf = (float*)(ws + 2 * (size_t)(1 << 18)); // 256 KB
  float* part = (float*)(ws + (1 << 20));             // 64 MB
  unsigned short* Wb = (unsigned short*)(ws + 65 * (size_t)(1 << 20));            // 128 MB
  unsigned short* xb = (unsigned short*)(ws + 65 * (size_t)(1 << 20) + WN * 2);   // 8 MB
  const size_t need_fast = 65 * (size_t)(1 << 20) + (size_t)WN * 2 + (size_t)XN * 2;
  const bool fast = ws_size >= need_fast;

  const dim3 grid(GR, 4);

  if (fast) {
    cvt_kernel<<<1024, 256, 0, stream>>>(x, xb, (int)(XN / 4));
    s0_kernel<true><<<grid, 256, 0, stream>>>(x, W, Wb, part);
  } else {
    s0_kernel<false><<<grid, 256, 0, stream>>>(x, W, Wb, part);
  }
  rs_kernel<<<256, 256, 0, stream>>>(part, vbuf);
  if (fast) a_kernel<true, true><<<grid, 256, 0, stream>>>(x, W, xb, Wb, vbuf, bb);
  else      a_kernel<false, true><<<grid, 256, 0, stream>>>(x, W, xb, Wb, vbuf, bb);
  softmax_kernel<<<NC, 256, 0, stream>>>(bb, cmat);
  if (fast) s_kernel<true><<<grid, 256, 0, stream>>>(x, W, xb, Wb, cmat, part);
  else      s_kernel<false><<<grid, 256, 0, stream>>>(x, W, xb, Wb, cmat, part);
  rs_kernel<<<256, 256, 0, stream>>>(part, vbuf);
  if (fast) a_kernel<true, false><<<grid, 256, 0, stream>>>(x, W, xb, Wb, vbuf, bb);
  else      a_kernel<false, false><<<grid, 256, 0, stream>>>(x, W, xb, Wb, vbuf, bb);
  softmax_kernel<<<NC, 256, 0, stream>>>(bb, cmat);
  if (fast) s_kernel<true><<<grid, 256, 0, stream>>>(x, W, xb, Wb, cmat, part);
  else      s_kernel<false><<<grid, 256, 0, stream>>>(x, W, xb, Wb, cmat, part);
  rs_kernel<<<256, 256, 0, stream>>>(part, out);
}

// Round 5
// 714.272 us; speedup vs baseline: 1.8103x; 1.0904x over previous
//
#include <hip/hip_runtime.h>
#include <hip/hip_bf16.h>

// Capsule routing: B=64, R=2048, C=32, O=32, I=32, 3 iterations.
// u_hat never materialized: recomputed per pass from bf16 W via MFMA.
// Round 5 (= round-4 intent, type fixed): hoisted W-load batches of 8 tiles
// for MLP, raised VGPR cap, NT-load of the one-shot f32 W stream using a
// native clang vector type (HIP float4 is rejected by the builtin).

#define B_  64
#define R_  2048
#define CI  32     // in channels (K)
#define NC  32     // num capsules
#define OC  32     // out channels
#define NCO 1024   // NC*OC, the N dimension
#define RPB 8      // routes per block
#define GR  (R_ / RPB)   // 256 blocks in r-dim
#define BN  65536  // B_*NCO elements of s/v

typedef __attribute__((ext_vector_type(8))) short bf16x8;
typedef __attribute__((ext_vector_type(4))) float f32x4;   // native clang vector

static constexpr long WN = (long)R_ * NCO * CI;  // 67,108,864
static constexpr long XN = (long)B_ * R_ * CI;   // 4,194,304

__device__ __forceinline__ unsigned short rne_bf16(float f) {
  unsigned int u = __builtin_bit_cast(unsigned int, f);
  u += 0x7fffu + ((u >> 16) & 1u);   // round-to-nearest-even (finite inputs)
  return (unsigned short)(u >> 16);
}

__device__ __forceinline__ bf16x8 pack8(f32x4 a, f32x4 b) {
  bf16x8 r;
  r[0] = (short)rne_bf16(a[0]); r[1] = (short)rne_bf16(a[1]);
  r[2] = (short)rne_bf16(a[2]); r[3] = (short)rne_bf16(a[3]);
  r[4] = (short)rne_bf16(b[0]); r[5] = (short)rne_bf16(b[1]);
  r[6] = (short)rne_bf16(b[2]); r[7] = (short)rne_bf16(b[3]);
  return r;
}

// f32 -> bf16, vectorized (n4 = n/4) — used for x only
__global__ __launch_bounds__(256) void cvt_kernel(const float* __restrict__ src,
                                                  unsigned short* __restrict__ dst,
                                                  int n4) {
  int i = blockIdx.x * blockDim.x + threadIdx.x;
  int stride = gridDim.x * blockDim.x;
  const f32x4* s4 = (const f32x4*)src;
  ushort4* d4 = (ushort4*)dst;
  for (; i < n4; i += stride) {
    f32x4 f = s4[i];
    ushort4 u;
    u.x = rne_bf16(f[0]); u.y = rne_bf16(f[1]);
    u.z = rne_bf16(f[2]); u.w = rne_bf16(f[3]);
    d4[i] = u;
  }
}

// Pass 0 s-pass fused with W conversion (c uniform = 1/2048): reads W f32
// (nontemporal — one-shot stream), converts inline, stores Wb, MFMA-accumulates.
// grid (GR, 4), block 256: wave mw = M-tile, blockIdx.y = g (8 capsules).
template<bool STORE_WB>
__global__ __launch_bounds__(256, 2) void s0_kernel(
    const float* __restrict__ x, const float* __restrict__ W,
    unsigned short* __restrict__ Wb,
    float* __restrict__ part) {          // [GR][B_][NCO]
  const int tid  = threadIdx.x;
  const int lane = tid & 63;
  const int mw   = tid >> 6;
  const int g    = blockIdx.y;
  const int r0   = blockIdx.x * RPB;
  const int l15  = lane & 15;
  const int q    = lane >> 4;
  const int k0   = q * 8;
  const int bA   = mw * 16 + l15;

  f32x4 acc[16];
#pragma unroll
  for (int t = 0; t < 16; ++t) acc[t] = (f32x4){0.f, 0.f, 0.f, 0.f};

  for (int j = 0; j < RPB; ++j) {
    const int r = r0 + j;
    const f32x4* xp = (const f32x4*)(x + ((bA * R_ + r) * CI + k0));
    bf16x8 af = pack8(xp[0], xp[1]);
#pragma unroll
    for (int half = 0; half < 2; ++half) {
      f32x4 w0[8], w1[8];
      // hoisted load phase: 16 independent dwordx4 in flight
#pragma unroll
      for (int tt = 0; tt < 8; ++tt) {
        const int t = half * 8 + tt;
        const int nrow = (g * 16 + t) * 16 + l15;
        const f32x4* wp = (const f32x4*)(W + (r * NCO + nrow) * CI + k0);
        w0[tt] = __builtin_nontemporal_load(wp);
        w1[tt] = __builtin_nontemporal_load(wp + 1);
      }
#pragma unroll
      for (int tt = 0; tt < 8; ++tt) {
        const int t = half * 8 + tt;
        const int nrow = (g * 16 + t) * 16 + l15;
        bf16x8 bfr = pack8(w0[tt], w1[tt]);
        if (STORE_WB && mw == (j & 3))
          *(bf16x8*)(Wb + (r * NCO + nrow) * CI + k0) = bfr;  // stored exactly once
        acc[t] = __builtin_amdgcn_mfma_f32_16x16x32_bf16(af, bfr, acc[t], 0, 0, 0);
      }
    }
  }
  // C/D layout: row(m) = (lane>>4)*4 + reg, col(n) = lane&15
  const int pbase = blockIdx.x * BN;
#pragma unroll
  for (int t = 0; t < 16; ++t) {
    const int n = (g * 16 + t) * 16 + l15;
#pragma unroll
    for (int rr = 0; rr < 4; ++rr) {
      const int b = mw * 16 + q * 4 + rr;
      part[pbase + b * NCO + n] = acc[t][rr] * (1.0f / 2048.0f);
    }
  }
}

// s-pass for iterations 1,2: s[b,c,o] partial = sum_r c[r,c]*(W[r,c,o,:].x[b,r,:])
template<bool FAST>
__global__ __launch_bounds__(256, 3) void s_kernel(
    const float* __restrict__ x, const float* __restrict__ W,
    const unsigned short* __restrict__ xb, const unsigned short* __restrict__ Wb,
    const float* __restrict__ cmat,   // [C][R]
    float* __restrict__ part) {       // [GR][B_][NCO]
  const int tid  = threadIdx.x;
  const int lane = tid & 63;
  const int mw   = tid >> 6;
  const int g    = blockIdx.y;
  const int r0   = blockIdx.x * RPB;
  const int l15  = lane & 15;
  const int q    = lane >> 4;
  const int k0   = q * 8;
  const int bA   = mw * 16 + l15;

  f32x4 acc[16];
#pragma unroll
  for (int t = 0; t < 16; ++t) acc[t] = (f32x4){0.f, 0.f, 0.f, 0.f};
  const f32x4 zero4 = (f32x4){0.f, 0.f, 0.f, 0.f};

  for (int j = 0; j < RPB; ++j) {
    const int r = r0 + j;
    bf16x8 af;
    if (FAST) {
      af = *(const bf16x8*)(xb + ((bA * R_ + r) * CI + k0));
    } else {
      const f32x4* xp = (const f32x4*)(x + ((bA * R_ + r) * CI + k0));
      af = pack8(xp[0], xp[1]);
    }
    float cv[8];
#pragma unroll
    for (int cc = 0; cc < 8; ++cc) cv[cc] = cmat[(g * 8 + cc) * R_ + r];
#pragma unroll
    for (int half = 0; half < 2; ++half) {
      bf16x8 wf[8];
#pragma unroll
      for (int tt = 0; tt < 8; ++tt) {
        const int t = half * 8 + tt;
        const int nrow = (g * 16 + t) * 16 + l15;
        if (FAST) wf[tt] = *(const bf16x8*)(Wb + (r * NCO + nrow) * CI + k0);
        else {
          const f32x4* wp = (const f32x4*)(W + (r * NCO + nrow) * CI + k0);
          wf[tt] = pack8(wp[0], wp[1]);
        }
      }
#pragma unroll
      for (int tt = 0; tt < 8; ++tt) {
        const int t = half * 8 + tt;
        f32x4 u = __builtin_amdgcn_mfma_f32_16x16x32_bf16(af, wf[tt], zero4, 0, 0, 0);
        acc[t] += cv[t >> 1] * u;  // capsule const within 16-wide n-tile (O=32)
      }
    }
  }
  const int pbase = blockIdx.x * BN;
#pragma unroll
  for (int t = 0; t < 16; ++t) {
    const int n = (g * 16 + t) * 16 + l15;
#pragma unroll
    for (int rr = 0; rr < 4; ++rr) {
      const int b = mw * 16 + q * 4 + rr;
      part[pbase + b * NCO + n] = acc[t][rr];
    }
  }
}

// reduce partials over GR slices + squash (exact reference formula)
__global__ __launch_bounds__(256) void rs_kernel(const float* __restrict__ part,
                                                 float* __restrict__ o) {
  const int i = blockIdx.x * 256 + threadIdx.x;
  float a0 = 0.f, a1 = 0.f, a2 = 0.f, a3 = 0.f;
  for (int p = 0; p < GR; p += 4) {
    a0 += part[p * BN + i];
    a1 += part[(p + 1) * BN + i];
    a2 += part[(p + 2) * BN + i];
    a3 += part[(p + 3) * BN + i];
  }
  const float sv = (a0 + a1) + (a2 + a3);
  const float sq = sv * sv;
  o[i] = sq * sv / ((1.0f + sq) * sqrtf(sq));
}

// a-pass: bb[c][r] (+)= (1/64) * sum_{b,o} u_hat[b,r,c,o] * v[b,c,o]
// Block (rg,g) exclusively owns bb[g*8..g*8+8][r0..r0+RPB] -> no atomics.
template<bool FAST, bool FIRST>
__global__ __launch_bounds__(256, 3) void a_kernel(
    const float* __restrict__ x, const float* __restrict__ W,
    const unsigned short* __restrict__ xb, const unsigned short* __restrict__ Wb,
    const float* __restrict__ v,    // [B_][NCO]
    float* __restrict__ bb) {       // [C][R]
  const int tid  = threadIdx.x;
  const int lane = tid & 63;
  const int mw   = tid >> 6;
  const int g    = blockIdx.y;
  const int r0   = blockIdx.x * RPB;
  const int l15  = lane & 15;
  const int q    = lane >> 4;
  const int k0   = q * 8;
  const int bA   = mw * 16 + l15;

  // pairs per chunk: 8 capsules x 4 routes = 32; 2 chunks cover 8 routes
  __shared__ float slab[4][32][65];     // [wave][pair][lane] 33.3 KB
  __shared__ float accw[2][4][64];      // [chunk][wave][pair-half] 2 KB

  // preload v in exact MFMA C-layout
  float vreg[16][4];
#pragma unroll
  for (int t = 0; t < 16; ++t) {
    const int n = (g * 16 + t) * 16 + l15;
#pragma unroll
    for (int rr = 0; rr < 4; ++rr)
      vreg[t][rr] = v[(mw * 16 + q * 4 + rr) * NCO + n];
  }
  const f32x4 zero4 = (f32x4){0.f, 0.f, 0.f, 0.f};

  for (int kk = 0; kk < 2; ++kk) {        // 2 chunks of 4 routes
#pragma unroll
    for (int jj = 0; jj < 4; ++jj) {
      const int r = r0 + kk * 4 + jj;
      bf16x8 af;
      if (FAST) {
        af = *(const bf16x8*)(xb + ((bA * R_ + r) * CI + k0));
      } else {
        const f32x4* xp = (const f32x4*)(x + ((bA * R_ + r) * CI + k0));
        af = pack8(xp[0], xp[1]);
      }
      float dotc[8];
#pragma unroll
      for (int cc = 0; cc < 8; ++cc) dotc[cc] = 0.f;
#pragma unroll
      for (int half = 0; half < 2; ++half) {
        bf16x8 wf[8];
#pragma unroll
        for (int tt = 0; tt < 8; ++tt) {
          const int t = half * 8 + tt;
          const int nrow = (g * 16 + t) * 16 + l15;
          if (FAST) wf[tt] = *(const bf16x8*)(Wb + (r * NCO + nrow) * CI + k0);
          else {
            const f32x4* wp = (const f32x4*)(W + (r * NCO + nrow) * CI + k0);
            wf[tt] = pack8(wp[0], wp[1]);
          }
        }
#pragma unroll
        for (int tt = 0; tt < 8; ++tt) {
          const int t = half * 8 + tt;
          f32x4 u = __builtin_amdgcn_mfma_f32_16x16x32_bf16(af, wf[tt], zero4, 0, 0, 0);
          dotc[t >> 1] += u[0] * vreg[t][0] + u[1] * vreg[t][1] +
                          u[2] * vreg[t][2] + u[3] * vreg[t][3];
        }
      }
      // stash: pair p = cc*4 + jj ; stride-1 in lane -> conflict-free
#pragma unroll
      for (int cc = 0; cc < 8; ++cc)
        slab[mw][cc * 4 + jj][lane] = dotc[cc];
    }
    // half-reduction: lane -> pair p=lane>>1, half h=lane&1 (32 each)
    {
      const int p = lane >> 1, h = lane & 1;
      float sm = 0.f;
#pragma unroll
      for (int i = 0; i < 32; ++i) sm += slab[mw][p][h * 32 + i];
      accw[kk][mw][lane] = sm;
    }
  }
  __syncthreads();
  // final: 64 threads = 2 chunks x 32 pairs
  if (tid < 64) {
    const int kk = tid >> 5;
    const int p  = tid & 31;
    float tot = 0.f;
#pragma unroll
    for (int w = 0; w < 4; ++w)
      tot += accw[kk][w][p * 2] + accw[kk][w][p * 2 + 1];
    const int cc = p >> 2, jj = p & 3;
    const int r  = r0 + kk * 4 + jj;
    const int o  = (g * 8 + cc) * R_ + r;
    const float val = tot * (1.0f / 64.0f);
    bb[o] = FIRST ? val : (bb[o] + val);
  }
}

// softmax over routes for each capsule: cmat[c][r] = softmax_r(bb[c][r])
__global__ __launch_bounds__(256) void softmax_kernel(const float* __restrict__ bb,
                                                      float* __restrict__ cmat) {
  const int c = blockIdx.x;
  const int tid = threadIdx.x;
  __shared__ float red[8];
  float m = -1e30f;
  for (int r = tid; r < R_; r += 256) m = fmaxf(m, bb[c * R_ + r]);
#pragma unroll
  for (int s = 1; s < 64; s <<= 1) m = fmaxf(m, __shfl_xor(m, s));
  if ((tid & 63) == 0) red[tid >> 6] = m;
  __syncthreads();
  m = fmaxf(fmaxf(red[0], red[1]), fmaxf(red[2], red[3]));
  float sum = 0.f;
  for (int r = tid; r < R_; r += 256) sum += __expf(bb[c * R_ + r] - m);
#pragma unroll
  for (int s = 1; s < 64; s <<= 1) sum += __shfl_xor(sum, s);
  if ((tid & 63) == 0) red[4 + (tid >> 6)] = sum;
  __syncthreads();
  sum = red[4] + red[5] + red[6] + red[7];
  const float inv = 1.0f / sum;
  for (int r = tid; r < R_; r += 256)
    cmat[c * R_ + r] = __expf(bb[c * R_ + r] - m) * inv;
}

extern "C" void kernel_launch(void* const* d_in, const int* in_sizes, int n_in,
                              void* d_out, int out_size, void* d_ws, size_t ws_size,
                              hipStream_t stream) {
  const float* x = (const float*)d_in[0];   // [64, 2048, 32]
  const float* W = (const float*)d_in[1];   // [2048, 32, 32, 32]
  float* out = (float*)d_out;               // [64, 32, 32, 1]

  char* ws = (char*)d_ws;
  float* bb   = (float*)(ws);                         // 256 KB
  float* cmat = (float*)(ws + (1 << 18));             // 256 KB
  float* vbuf = (float*)(ws + 2 * (size_t)(1 << 18)); // 256 KB
  float* part = (float*)(ws + (1 << 20));             // 64 MB
  unsigned short* Wb = (unsigned short*)(ws + 65 * (size_t)(1 << 20));            // 128 MB
  unsigned short* xb = (unsigned short*)(ws + 65 * (size_t)(1 << 20) + WN * 2);   // 8 MB
  const size_t need_fast = 65 * (size_t)(1 << 20) + (size_t)WN * 2 + (size_t)XN * 2;
  const bool fast = ws_size >= need_fast;

  const dim3 grid(GR, 4);

  if (fast) {
    cvt_kernel<<<1024, 256, 0, stream>>>(x, xb, (int)(XN / 4));
    s0_kernel<true><<<grid, 256, 0, stream>>>(x, W, Wb, part);
  } else {
    s0_kernel<false><<<grid, 256, 0, stream>>>(x, W, Wb, part);
  }
  rs_kernel<<<256, 256, 0, stream>>>(part, vbuf);
  if (fast) a_kernel<true, true><<<grid, 256, 0, stream>>>(x, W, xb, Wb, vbuf, bb);
  else      a_kernel<false, true><<<grid, 256, 0, stream>>>(x, W, xb, Wb, vbuf, bb);
  softmax_kernel<<<NC, 256, 0, stream>>>(bb, cmat);
  if (fast) s_kernel<true><<<grid, 256, 0, stream>>>(x, W, xb, Wb, cmat, part);
  else      s_kernel<false><<<grid, 256, 0, stream>>>(x, W, xb, Wb, cmat, part);
  rs_kernel<<<256, 256, 0, stream>>>(part, vbuf);
  if (fast) a_kernel<true, false><<<grid, 256, 0, stream>>>(x, W, xb, Wb, vbuf, bb);
  else      a_kernel<false, false><<<grid, 256, 0, stream>>>(x, W, xb, Wb, vbuf, bb);
  softmax_kernel<<<NC, 256, 0, stream>>>(bb, cmat);
  if (fast) s_kernel<true><<<grid, 256, 0, stream>>>(x, W, xb, Wb, cmat, part);
  else      s_kernel<false><<<grid, 256, 0, stream>>>(x, W, xb, Wb, cmat, part);
  rs_kernel<<<256, 256, 0, stream>>>(part, out);
}